// Round 8
// baseline (169.230 us; speedup 1.0000x reference)
//
#include <hip/hip_runtime.h>
#include <hip/hip_bf16.h>

#define SS 4096
#define NROW 16384

typedef __attribute__((ext_vector_type(8))) short short8;
typedef __attribute__((ext_vector_type(4))) float f32x4;
typedef _Float16 half4 __attribute__((ext_vector_type(4)));

#define AS1 __attribute__((address_space(1)))
#define AS3 __attribute__((address_space(3)))

static __device__ __forceinline__ void glds16(const void* g, void* l) {
    __builtin_amdgcn_global_load_lds((const AS1 unsigned*)g, (AS3 unsigned*)l, 16, 0, 0);
}
static __device__ __forceinline__ short f2bf(float f) {           // RNE
    union { float f; unsigned u; } v; v.f = f;
    unsigned r = v.u + 0x7FFFu + ((v.u >> 16) & 1u);
    return (short)(r >> 16);
}
static __device__ __forceinline__ unsigned pkbf(float lo, float hi) {
    union { float f; unsigned u; } x, y; x.f = lo; y.f = hi;
    return __builtin_amdgcn_perm(y.u + 0x8000u, x.u + 0x8000u, 0x07060302);
}
static __device__ __forceinline__ float bf2f(short s) {
    union { unsigned u; float f; } v;
    v.u = ((unsigned)(unsigned short)s) << 16;
    return v.f;
}

// ---------------- pack W: [1024][64] fp32 x3 -> Wpack[n=192][k=1024] bf16 (LDS transpose) ----------------
__global__ __launch_bounds__(256) void pack_w(const float* __restrict__ Wq,
                                              const float* __restrict__ Wk,
                                              const float* __restrict__ Wv,
                                              short* __restrict__ Wpack) {
    __shared__ float T[64 * 65];
    int bid = blockIdx.x;                 // 48 = 3 n-blocks x 16 k-blocks
    int nb = bid >> 4, kb = bid & 15;
    const float* W = (nb == 0) ? Wq : (nb == 1 ? Wk : Wv);
    int n0 = nb * 64, k0 = kb * 64;
    int tid = threadIdx.x;
    for (int ps = 0; ps < 16; ++ps) {
        int idx = tid + ps * 256;
        int kk = idx >> 6, nn = idx & 63;
        T[kk * 65 + nn] = W[(k0 + kk) * 64 + nn];
    }
    __syncthreads();
    for (int ps = 0; ps < 16; ++ps) {
        int idx = tid + ps * 256;
        int nn = idx >> 6, kk = idx & 63;
        Wpack[(n0 + nn) * 1024 + k0 + kk] = f2bf(T[kk * 65 + nn]);
    }
}

// ---------- proj: 1024 blocks x 256 thr; 16 rows x 192 cols; BK=32; glds double-buffer ----------
// Grid doubled + LDS shrunk (28.7 KB) -> 4 resident blocks/CU to overlap the barrier drains.
// All 4 waves share the 16-row A-tile; wave wv owns cols [wv*48, wv*48+48).
__global__ __launch_bounds__(256, 4) void proj_qkv(const float* __restrict__ x,
                                                   const short* __restrict__ Wpack,
                                                   const float* __restrict__ bq,
                                                   const float* __restrict__ bk,
                                                   const float* __restrict__ bv,
                                                   short* __restrict__ Qg,
                                                   short* __restrict__ Kg,
                                                   short* __restrict__ Vt) {
    __shared__ float Xs[2][16 * 32];      // x tile fp32, chunk-swizzled (^row&7)
    __shared__ short Wsm[2][192 * 32];    // W tile bf16, chunk-swizzled (^(row>>1)&3)
    int tid = threadIdx.x, lane = tid & 63, wv = tid >> 6;
    int g = lane >> 4, c = lane & 15;
    int rowbase = blockIdx.x * 16;

    f32x4 acc[3];
    for (int i = 0; i < 3; ++i) acc[i] = (f32x4)(0.f);

    // x staging: 128 units of 16B (16 rows x 8 chunks); waves 0-1 only
    int xrow = tid >> 3, xq = tid & 7;
    int xsrc = xq ^ (xrow & 7);
    // W staging: 768 units (192 rows x 4 chunks); 3 per thread
    // unit u = (wv*3+j)*64 + lane -> row u>>2, chunk u&3, src chunk (u&3)^((row>>1)&3)

#define PROJ_ISSUE(nbs, k0)                                                               \
    do {                                                                                  \
        if (tid < 128)                                                                    \
            glds16(x + (rowbase + xrow) * 1024 + (k0) + xsrc * 4, &Xs[nbs][tid * 4]);     \
        for (int j = 0; j < 3; ++j) {                                                     \
            int u = (wv * 3 + j) * 64 + lane;                                             \
            int wr = u >> 2, wq = u & 3;                                                  \
            glds16(Wpack + wr * 1024 + (k0) + (wq ^ ((wr >> 1) & 3)) * 8,                 \
                   &Wsm[nbs][u * 8]);                                                     \
        }                                                                                 \
    } while (0)

    PROJ_ISSUE(0, 0);

    for (int ko = 0; ko < 32; ++ko) {
        int bs = ko & 1;
        __syncthreads();                       // drains glds(ko), syncs waves
        if (ko < 31) PROJ_ISSUE(bs ^ 1, (ko + 1) * 32);
        // A-frag: row c, k = g*8..g*8+7  (fp32 chunks 2g, 2g+1, swizzled by row)
        float4 xa = *reinterpret_cast<const float4*>(&Xs[bs][c * 32 + ((2 * g) ^ (c & 7)) * 4]);
        float4 xb = *reinterpret_cast<const float4*>(&Xs[bs][c * 32 + ((2 * g + 1) ^ (c & 7)) * 4]);
        short8 a;
        unsigned* aw = (unsigned*)&a;
        aw[0] = pkbf(xa.x, xa.y); aw[1] = pkbf(xa.z, xa.w);
        aw[2] = pkbf(xb.x, xb.y); aw[3] = pkbf(xb.z, xb.w);
        for (int nt = 0; nt < 3; ++nt) {
            int wrow = wv * 48 + nt * 16 + c;
            short8 b = *reinterpret_cast<const short8*>(
                &Wsm[bs][wrow * 32 + (g ^ ((wrow >> 1) & 3)) * 8]);
            acc[nt] = __builtin_amdgcn_mfma_f32_16x16x32_bf16(a, b, acc[nt], 0, 0, 0);
        }
    }
#undef PROJ_ISSUE

    const float SCQ = 0.125f * 1.4426950408889634f;   // fold score scale + log2e into Q
    _Float16* Vh = (_Float16*)Vt;
    for (int nt = 0; nt < 3; ++nt) {
        int col = wv * 48 + nt * 16 + c;
        for (int r = 0; r < 4; ++r) {
            int grow = rowbase + g * 4 + r;
            float vv = acc[nt][r];
            if (col < 64) {
                Qg[grow * 64 + col] = f2bf((vv + bq[col]) * SCQ);
            } else if (col < 128) {
                Kg[grow * 64 + (col - 64)] = f2bf(vv + bk[col - 64]);
            } else {
                int f = col - 128;
                int batch = grow >> 12, s = grow & 4095;
                int key = s & 63;
                // f16, tile-blocked, key XOR-swizzled for conflict-free A-frag LDS reads in attn
                Vh[batch * 262144 + (s >> 6) * 4096 + f * 64 + (key ^ ((f & 15) * 4))] =
                    (_Float16)(vv + bv[f]);
            }
        }
    }
}

// ---------- attn: glds-staged K/V, S^T trick -> P stays in registers, PV via 16x16x16 f16 ----------
__global__ __launch_bounds__(256, 4) void attn(const short* __restrict__ Qg,
                                               const short* __restrict__ Kg,
                                               const short* __restrict__ Vt,
                                               short* __restrict__ Opart,
                                               float* __restrict__ Ls) {
    __shared__ short Kbuf[2][64 * 64];
    __shared__ short Vbuf[2][64 * 64];
    int tid = threadIdx.x, lane = tid & 63, wv = tid >> 6;
    int g = lane >> 4, c = lane & 15;

    // decode bid -> (batch, p, ch); reversed so biggest-p blocks dispatch first
    int rb = 1151 - blockIdx.x;
    int batch = rb / 288;
    int j = rb - batch * 288;
    int gq = (int)((sqrtf((float)j + 1.0f) - 1.0f) * 0.5f);
    while (4 * (gq + 1) * (gq + 2) <= j) ++gq;
    while (4 * gq * (gq + 1) > j) --gq;
    int rem = j - 4 * gq * (gq + 1);
    int pidx = rem / (gq + 1);
    int ch = rem - pidx * (gq + 1);
    int p = gq * 8 + pidx;

    int t0 = ch * 8, t1 = min(t0 + 8, p + 1);
    int qrow0 = batch * SS + p * 64;
    const short* Kb = Kg + batch * SS * 64;
    const short* Vb = Vt + batch * SS * 64;

    // Q B-frags (qrow = qrow0 + wv*16 + c)
    short8 aq0 = *reinterpret_cast<const short8*>(Qg + (qrow0 + wv * 16 + c) * 64 + g * 8);
    short8 aq1 = *reinterpret_cast<const short8*>(Qg + (qrow0 + wv * 16 + c) * 64 + 32 + g * 8);

    f32x4 acc_o[4];                       // O^T: [ft] -> feat = ft*16 + g*4 + r, qrow = c
    for (int f = 0; f < 4; ++f) acc_o[f] = (f32x4)(0.f);
    float rs = 0.f;                       // per-lane partial l (qrow=c, keys of this g-group)

    // staging: K source-swizzled (chunk ^ row), V identity (swizzle baked into global layout)
    int s0 = wv * 128 + lane, s1 = s0 + 64;
    int r0 = s0 >> 3, q0 = (s0 & 7) ^ (r0 & 7);
    int r1 = s1 >> 3, q1 = (s1 & 7) ^ (r1 & 7);

#define ATTN_ISSUE(nbs, t)                                                  \
    do {                                                                    \
        glds16(Kb + (t) * 4096 + r0 * 64 + q0 * 8, &Kbuf[nbs][s0 * 8]);     \
        glds16(Kb + (t) * 4096 + r1 * 64 + q1 * 8, &Kbuf[nbs][s1 * 8]);     \
        glds16(Vb + (t) * 4096 + s0 * 8, &Vbuf[nbs][s0 * 8]);               \
        glds16(Vb + (t) * 4096 + s1 * 8, &Vbuf[nbs][s1 * 8]);               \
    } while (0)

    ATTN_ISSUE(0, t0);

    for (int t = t0; t < t1; ++t) {
        int bs = (t - t0) & 1;
        __syncthreads();
        if (t + 1 < t1) ATTN_ISSUE(bs ^ 1, t + 1);

        // S^T = K·Q^T : C-layout holds key = nt*16 + g*4 + r, qrow = c
        f32x4 s[4];
#pragma unroll
        for (int nt = 0; nt < 4; ++nt) {
            short8 k0 = *reinterpret_cast<const short8*>(&Kbuf[bs][(nt * 16 + c) * 64 + ((g) ^ (c & 7)) * 8]);
            short8 k1 = *reinterpret_cast<const short8*>(&Kbuf[bs][(nt * 16 + c) * 64 + ((g + 4) ^ (c & 7)) * 8]);
            s[nt] = (f32x4)(0.f);
            s[nt] = __builtin_amdgcn_mfma_f32_16x16x32_bf16(k0, aq0, s[nt], 0, 0, 0);
            s[nt] = __builtin_amdgcn_mfma_f32_16x16x32_bf16(k1, aq1, s[nt], 0, 0, 0);
        }

        // fixed-max softmax in registers; P^T is directly the 16x16x16 B-operand layout
        half4 pb[4];
        if (t == p) {      // diagonal tile: causal mask (key > qrow)
#pragma unroll
            for (int nt = 0; nt < 4; ++nt)
                for (int r = 0; r < 4; ++r) {
                    int key = nt * 16 + g * 4 + r;
                    int row = wv * 16 + c;
                    float pv = (key <= row) ? __builtin_amdgcn_exp2f(s[nt][r]) : 0.f;
                    rs += pv;
                    pb[nt][r] = (_Float16)pv;
                }
        } else {
#pragma unroll
            for (int nt = 0; nt < 4; ++nt)
                for (int r = 0; r < 4; ++r) {
                    float pv = __builtin_amdgcn_exp2f(s[nt][r]);
                    rs += pv;
                    pb[nt][r] = (_Float16)pv;
                }
        }

        // O^T += V^T · P^T  (A = V^T f16 b64 frags from LDS, B = P^T in regs)
#pragma unroll
        for (int nt = 0; nt < 4; ++nt) {
#pragma unroll
            for (int ft = 0; ft < 4; ++ft) {
                half4 va = *reinterpret_cast<const half4*>(
                    &Vbuf[bs][(ft * 16 + c) * 64 + ((nt * 16 + g * 4) ^ (c * 4))]);
                acc_o[ft] = __builtin_amdgcn_mfma_f32_16x16x16f16(va, pb[nt], acc_o[ft], 0, 0, 0);
            }
        }
    }
#undef ATTN_ISSUE

    // l for qrow=c: sum partials across the 4 g-groups (lanes differing in bits 4-5)
    float l = rs;
    l += __shfl_xor(l, 16);
    l += __shfl_xor(l, 32);
    float inv = 1.0f / l;

    int slot = ((batch * 64 + p) << 3) + ch;
    short* op = Opart + slot * 4096;
    int row = wv * 16 + c;
#pragma unroll
    for (int ft = 0; ft < 4; ++ft) {
        short4 ov;
        ov.x = f2bf(acc_o[ft][0] * inv);
        ov.y = f2bf(acc_o[ft][1] * inv);
        ov.z = f2bf(acc_o[ft][2] * inv);
        ov.w = f2bf(acc_o[ft][3] * inv);
        *reinterpret_cast<short4*>(op + row * 64 + ft * 16 + g * 4) = ov;
    }
    if (g == 0)
        Ls[slot * 64 + wv * 16 + c] = l;
}

// ---------- merge <=8 chunks per (batch,P): out = sum(l_i * O_i) / sum(l_i) ----------
__global__ __launch_bounds__(256) void merge_k(const short* __restrict__ Opart,
                                               const float* __restrict__ Ls,
                                               float* __restrict__ out) {
    int bP = blockIdx.x;               // batch*64 + P
    int P = bP & 63, batch = bP >> 6;
    int nch = (P + 8) >> 3;            // ceil((P+1)/8)
    int tid = threadIdx.x;
    int row = tid & 63, fg = tid >> 6;
    int slot0 = bP << 3;

    float w[8];
    float wsum = 0.f;
    for (int i = 0; i < nch; ++i) { w[i] = Ls[(slot0 + i) * 64 + row]; wsum += w[i]; }
    float invw = 1.0f / wsum;

    float o[16];
    for (int jj = 0; jj < 16; ++jj) o[jj] = 0.f;
    for (int i = 0; i < nch; ++i) {
        const short* op = Opart + (slot0 + i) * 4096 + row * 64 + fg * 16;
        short8 v0 = *reinterpret_cast<const short8*>(op);
        short8 v1 = *reinterpret_cast<const short8*>(op + 8);
        for (int jj = 0; jj < 8; ++jj) {
            o[jj]     += w[i] * bf2f(v0[jj]);
            o[8 + jj] += w[i] * bf2f(v1[jj]);
        }
    }
    int orow = batch * SS + P * 64 + row;
    for (int jj = 0; jj < 16; jj += 4) {
        float4 v;
        v.x = o[jj] * invw; v.y = o[jj + 1] * invw; v.z = o[jj + 2] * invw; v.w = o[jj + 3] * invw;
        *reinterpret_cast<float4*>(out + orow * 64 + fg * 16 + jj) = v;
    }
}

extern "C" void kernel_launch(void* const* d_in, const int* in_sizes, int n_in,
                              void* d_out, int out_size, void* d_ws, size_t ws_size,
                              hipStream_t stream) {
    const float* x  = (const float*)d_in[0];
    const float* Wq = (const float*)d_in[1];
    const float* bq = (const float*)d_in[2];
    const float* Wk = (const float*)d_in[3];
    const float* bk = (const float*)d_in[4];
    const float* Wv = (const float*)d_in[5];
    const float* bv = (const float*)d_in[6];
    float* out = (float*)d_out;

    short* Wpack = (short*)d_ws;                    // 196608 shorts
    short* Qg    = Wpack + 196608;                  // 1048576
    short* Kg    = Qg + NROW * 64;                  // 1048576
    short* Vt    = Kg + NROW * 64;                  // 1048576 (f16, tile-blocked + swizzled)
    short* Opart = Vt + NROW * 64;                  // 2048*4096
    float* Ls    = (float*)(Opart + 2048 * 4096);   // 2048*64 floats

    hipLaunchKernelGGL(pack_w,   dim3(48),   dim3(256), 0, stream, Wq, Wk, Wv, Wpack);
    hipLaunchKernelGGL(proj_qkv, dim3(1024), dim3(256), 0, stream, x, Wpack, bq, bk, bv, Qg, Kg, Vt);
    hipLaunchKernelGGL(attn,     dim3(1152), dim3(256), 0, stream, Qg, Kg, Vt, Opart, Ls);
    hipLaunchKernelGGL(merge_k,  dim3(256),  dim3(256), 0, stream, Opart, Ls, out);
}